// Round 8
// baseline (1828.548 us; speedup 1.0000x reference)
//
#include <hip/hip_runtime.h>
#include <math.h>

#define N_NODES 100000
#define N_EDGES 1600000
#define HDIM 128
#define NBLK 16
#define NREL 200
#define NW_AGG 8192  // balanced waves: 256 CU x 32 waves, exact fill

typedef unsigned short ushort_t;
typedef unsigned int uint_t;
typedef _Float16 h2 __attribute__((ext_vector_type(2)));

__device__ __forceinline__ ushort_t f2h(float f) {
  _Float16 h = (_Float16)f;
  return __builtin_bit_cast(unsigned short, h);
}
__device__ __forceinline__ float h2f(ushort_t b) {
  return (float)__builtin_bit_cast(_Float16, b);
}

// acc += a.lo*b.lo + a.hi*b.hi  (packed f16 pairs, f32 accumulate)
#if defined(__has_builtin) && __has_builtin(__builtin_amdgcn_fdot2)
#define FDOT2(accv, au, bu)                                                    \
  accv = __builtin_amdgcn_fdot2(__builtin_bit_cast(h2, au),                    \
                                __builtin_bit_cast(h2, bu), accv, false);
#else
#define FDOT2(accv, au, bu)                                                    \
  {                                                                            \
    h2 av_ = __builtin_bit_cast(h2, au);                                       \
    h2 bv_ = __builtin_bit_cast(h2, bu);                                       \
    accv = fmaf((float)av_[0], (float)bv_[0], accv);                           \
    accv = fmaf((float)av_[1], (float)bv_[1], accv);                           \
  }
#endif

// ================= CSR build (dst -> packed edge records) =================
__global__ __launch_bounds__(256) void hist_deg(const int* __restrict__ dst,
                                                int* __restrict__ deg) {
  int e = blockIdx.x * 256 + threadIdx.x;
  if (e < N_EDGES) atomicAdd(&deg[dst[e]], 1);
}

// exclusive scan; also writes offsets[N_NODES] = E
__global__ __launch_bounds__(1024) void scan_offsets(const int* __restrict__ deg,
                                                     int* __restrict__ offsets) {
  __shared__ int wsum[16];
  __shared__ int carry_s;
  int tid = threadIdx.x, lane = tid & 63, wid = tid >> 6;
  if (tid == 0) carry_s = 0;
  __syncthreads();
  for (int base = 0; base < N_NODES; base += 1024) {
    int i = base + tid;
    int v = (i < N_NODES) ? deg[i] : 0;
    int x = v;
#pragma unroll
    for (int s = 1; s < 64; s <<= 1) {
      int t = __shfl_up(x, s);
      if (lane >= s) x += t;
    }
    if (lane == 63) wsum[wid] = x;
    __syncthreads();
    if (wid == 0) {
      int y = (lane < 16) ? wsum[lane] : 0;
#pragma unroll
      for (int s = 1; s < 16; s <<= 1) {
        int t = __shfl_up(y, s);
        if (lane >= s) y += t;
      }
      if (lane < 16) wsum[lane] = y;
    }
    __syncthreads();
    int carry = carry_s;
    int wbase = (wid > 0) ? wsum[wid - 1] : 0;
    if (i < N_NODES) offsets[i] = carry + wbase + (x - v);
    __syncthreads();
    if (tid == 0) carry_s = carry + wsum[15];
    __syncthreads();
  }
  if (tid == 0) offsets[N_NODES] = carry_s;  // == N_EDGES
}

__global__ __launch_bounds__(256) void scatter_rec(
    const int* __restrict__ src, const int* __restrict__ dst,
    const int* __restrict__ etype, const float* __restrict__ norm,
    const int* __restrict__ offsets, int* __restrict__ cursor,
    int4* __restrict__ rec) {
  int e = blockIdx.x * 256 + threadIdx.x;
  if (e >= N_EDGES) return;
  int d = dst[e];
  int pos = offsets[d] + atomicAdd(&cursor[d], 1);
  rec[pos] = make_int4(src[e], etype[e], __float_as_int(norm[e]), 0);
}

// wave w owns nodes [ranges[w], ranges[w+1]) ; node n -> wave floor(off[n]*NW/E)
__global__ __launch_bounds__(256) void calc_ranges(const int* __restrict__ offsets,
                                                   int* __restrict__ ranges) {
  int w = blockIdx.x * 256 + threadIdx.x;
  if (w > NW_AGG) return;
  if (w == NW_AGG) {
    ranges[w] = N_NODES;
    return;
  }
  long t = ((long)w * N_EDGES + NW_AGG - 1) / NW_AGG;  // ceil(w*E/NW)
  int lo = 0, hi = N_NODES;
  while (lo < hi) {
    int mid = (lo + hi) >> 1;
    if ((long)offsets[mid] >= t) hi = mid;
    else lo = mid + 1;
  }
  ranges[w] = lo;
}

// f16 copy of gathered embeddings
__global__ __launch_bounds__(256) void conv_h0(const int* __restrict__ node_ids,
                                               const float* __restrict__ emb,
                                               ushort_t* __restrict__ h0h) {
  long gid = (long)blockIdx.x * 256 + threadIdx.x;
  if (gid >= (long)N_NODES * HDIM) return;
  int n = (int)(gid >> 7);
  int o = (int)(gid & 127);
  h0h[gid] = f2h(emb[(long)node_ids[n] * HDIM + o]);
}

// W1 (R,NB,8,8) fp32 -> Wh1 [rb][g(4)][c(2)][ip(4)][hi(2)] f16 (i = ip*2+hi, o = g*2+c)
__global__ __launch_bounds__(256) void conv_w1(const float* __restrict__ W,
                                               ushort_t* __restrict__ Wh) {
  int idx = blockIdx.x * 256 + threadIdx.x;
  if (idx >= NREL * NBLK * 64) return;
  int rb = idx >> 6, i = (idx >> 3) & 7, o = idx & 7;
  int g = o >> 1, c = o & 1, ip = i >> 1, hi = i & 1;
  Wh[(((rb * 4 + g) * 2 + c) * 4 + ip) * 2 + hi] = f2h(W[idx]);
}

// W2 (R,NB,8,16) fp32 -> Wh2 [rb][g(4)][c(4)][ip(4)][hi(2)] f16 (i = ip*2+hi, o = g*4+c)
__global__ __launch_bounds__(256) void conv_w2(const float* __restrict__ W,
                                               ushort_t* __restrict__ Wh) {
  int idx = blockIdx.x * 256 + threadIdx.x;
  if (idx >= NREL * NBLK * 128) return;
  int rb = idx >> 7, i = (idx >> 4) & 7, o = idx & 15;
  int g = o >> 2, c = o & 3, ip = i >> 1, hi = i & 1;
  Wh[(((rb * 4 + g) * 4 + c) * 4 + ip) * 2 + hi] = f2h(W[idx]);
}

// ================= Layer-1 aggregation: balanced waves =================
// lane l: block b = l>>2, col-group g = l&3 (cols g*2, g*2+1)
__global__ __launch_bounds__(256, 8) void agg_layer1(
    const int4* __restrict__ rec, const int* __restrict__ offsets,
    const int* __restrict__ ranges, const ushort_t* __restrict__ h0h,
    const ushort_t* __restrict__ Wh, float* __restrict__ agg) {
  int w = blockIdx.x * 4 + (threadIdx.x >> 6);
  int l = threadIdx.x & 63;
  int b = l >> 2, g = l & 3;
  int lo = ranges[w], hi = ranges[w + 1];
  if (lo >= hi) return;
  int estart = offsets[lo];
  int ecnt = offsets[hi] - estart;
  int cur = lo;
  int next_b = offsets[lo + 1];
  float acc0 = 0.f, acc1 = 0.f;

#define FLUSH1                                                                 \
  {                                                                            \
    float2 res = {acc0, acc1};                                                 \
    *(float2*)(agg + (long)cur * HDIM + l * 2) = res;                          \
    acc0 = acc1 = 0.f;                                                         \
    ++cur;                                                                     \
    next_b = offsets[cur + 1];                                                 \
  }
#define BCHK1(kk)                                                              \
  {                                                                            \
    int eid = estart + c0 + kk;                                                \
    while (eid == next_b) FLUSH1                                               \
  }
#define LOAD1(U, W0, W1, kk)                                                   \
  {                                                                            \
    int ss = __shfl(r.x, kk), tt = __shfl(r.y, kk);                            \
    U = *(const uint4*)(h0h + ((long)ss << 7) + (b << 3));                     \
    const uint4* Wp =                                                          \
        (const uint4*)(Wh + (((size_t)((tt << 4) + b) << 2) + g) * 16);        \
    W0 = Wp[0];                                                                \
    W1 = Wp[1];                                                                \
  }
#define COMP1(U, W0, W1, kk)                                                   \
  {                                                                            \
    float nn = __uint_as_float((uint_t)__shfl(r.z, kk));                       \
    float p0 = 0.f, p1 = 0.f;                                                  \
    FDOT2(p0, U.x, W0.x) FDOT2(p0, U.y, W0.y)                                  \
    FDOT2(p0, U.z, W0.z) FDOT2(p0, U.w, W0.w)                                  \
    FDOT2(p1, U.x, W1.x) FDOT2(p1, U.y, W1.y)                                  \
    FDOT2(p1, U.z, W1.z) FDOT2(p1, U.w, W1.w)                                  \
    acc0 = fmaf(p0, nn, acc0);                                                 \
    acc1 = fmaf(p1, nn, acc1);                                                 \
  }

  for (int c0 = 0; c0 < ecnt; c0 += 64) {
    int m = min(64, ecnt - c0);
    int4 r = make_int4(0, 0, 0, 0);
    if (l < m) r = rec[estart + c0 + l];
    uint4 uA, wA0, wA1, uB, wB0, wB1;
    LOAD1(uA, wA0, wA1, 0)
    int k = 0;
    while (true) {
      BCHK1(k)
      if (k + 1 < m) LOAD1(uB, wB0, wB1, k + 1)
      COMP1(uA, wA0, wA1, k)
      if (++k >= m) break;
      BCHK1(k)
      if (k + 1 < m) LOAD1(uA, wA0, wA1, k + 1)
      COMP1(uB, wB0, wB1, k)
      if (++k >= m) break;
    }
  }
  // final flush: last node + trailing deg-0 nodes
  while (cur < hi) {
    float2 res = {acc0, acc1};
    *(float2*)(agg + (long)cur * HDIM + l * 2) = res;
    acc0 = acc1 = 0.f;
    ++cur;
  }
#undef FLUSH1
#undef BCHK1
#undef LOAD1
#undef COMP1
}

// ================= Layer-2 aggregation: balanced waves =================
// lane l: block b = l>>2, col-group g = l&3 (cols g*4..g*4+3)
__global__ __launch_bounds__(256, 8) void agg_layer2(
    const int4* __restrict__ rec, const int* __restrict__ offsets,
    const int* __restrict__ ranges, const ushort_t* __restrict__ h1h,
    const ushort_t* __restrict__ Wh, float* __restrict__ agg) {
  int w = blockIdx.x * 4 + (threadIdx.x >> 6);
  int l = threadIdx.x & 63;
  int b = l >> 2, g = l & 3;
  int lo = ranges[w], hi = ranges[w + 1];
  if (lo >= hi) return;
  int estart = offsets[lo];
  int ecnt = offsets[hi] - estart;
  int cur = lo;
  int next_b = offsets[lo + 1];
  float ax = 0.f, ay = 0.f, az = 0.f, aw = 0.f;

#define FLUSH2                                                                 \
  {                                                                            \
    float4 res = {ax, ay, az, aw};                                             \
    *(float4*)(agg + (long)cur * 256 + l * 4) = res;                           \
    ax = ay = az = aw = 0.f;                                                   \
    ++cur;                                                                     \
    next_b = offsets[cur + 1];                                                 \
  }
#define BCHK2(kk)                                                              \
  {                                                                            \
    int eid = estart + c0 + kk;                                                \
    while (eid == next_b) FLUSH2                                               \
  }
#define LOAD2(U, Q0, Q1, Q2, Q3, kk)                                           \
  {                                                                            \
    int ss = __shfl(r.x, kk), tt = __shfl(r.y, kk);                            \
    U = *(const uint4*)(h1h + ((long)ss << 7) + (b << 3));                     \
    const uint4* Wp =                                                          \
        (const uint4*)(Wh + (((size_t)((tt << 4) + b) << 2) + g) * 32);        \
    Q0 = Wp[0];                                                                \
    Q1 = Wp[1];                                                                \
    Q2 = Wp[2];                                                                \
    Q3 = Wp[3];                                                                \
  }
#define COMP2(U, Q0, Q1, Q2, Q3, kk)                                           \
  {                                                                            \
    float nn = __uint_as_float((uint_t)__shfl(r.z, kk));                       \
    float px = 0.f, py = 0.f, pz = 0.f, pw = 0.f;                              \
    FDOT2(px, U.x, Q0.x) FDOT2(px, U.y, Q0.y)                                  \
    FDOT2(px, U.z, Q0.z) FDOT2(px, U.w, Q0.w)                                  \
    FDOT2(py, U.x, Q1.x) FDOT2(py, U.y, Q1.y)                                  \
    FDOT2(py, U.z, Q1.z) FDOT2(py, U.w, Q1.w)                                  \
    FDOT2(pz, U.x, Q2.x) FDOT2(pz, U.y, Q2.y)                                  \
    FDOT2(pz, U.z, Q2.z) FDOT2(pz, U.w, Q2.w)                                  \
    FDOT2(pw, U.x, Q3.x) FDOT2(pw, U.y, Q3.y)                                  \
    FDOT2(pw, U.z, Q3.z) FDOT2(pw, U.w, Q3.w)                                  \
    ax = fmaf(px, nn, ax);                                                     \
    ay = fmaf(py, nn, ay);                                                     \
    az = fmaf(pz, nn, az);                                                     \
    aw = fmaf(pw, nn, aw);                                                     \
  }

  for (int c0 = 0; c0 < ecnt; c0 += 64) {
    int m = min(64, ecnt - c0);
    int4 r = make_int4(0, 0, 0, 0);
    if (l < m) r = rec[estart + c0 + l];
    uint4 uA, qA0, qA1, qA2, qA3, uB, qB0, qB1, qB2, qB3;
    LOAD2(uA, qA0, qA1, qA2, qA3, 0)
    int k = 0;
    while (true) {
      BCHK2(k)
      if (k + 1 < m) LOAD2(uB, qB0, qB1, qB2, qB3, k + 1)
      COMP2(uA, qA0, qA1, qA2, qA3, k)
      if (++k >= m) break;
      BCHK2(k)
      if (k + 1 < m) LOAD2(uA, qA0, qA1, qA2, qA3, k + 1)
      COMP2(uB, qB0, qB1, qB2, qB3, k)
      if (++k >= m) break;
    }
  }
  while (cur < hi) {
    float4 res = {ax, ay, az, aw};
    *(float4*)(agg + (long)cur * 256 + l * 4) = res;
    ax = ay = az = aw = 0.f;
    ++cur;
  }
#undef FLUSH2
#undef BCHK2
#undef LOAD2
#undef COMP2
}

// ================= Node kernels (dense self-loop + epilogue) =================
__global__ __launch_bounds__(256) void node_layer1(
    const int* __restrict__ node_ids, const float* __restrict__ emb,
    const float* __restrict__ loop1, const float* __restrict__ agg1,
    const float* __restrict__ bias, ushort_t* __restrict__ h1h) {
  __shared__ float L[HDIM * HDIM];
  __shared__ float hs[2][HDIM];
  for (int idx = threadIdx.x; idx < HDIM * HDIM; idx += 256) L[idx] = loop1[idx];
  __syncthreads();
  int o = threadIdx.x & 127;
  int sub = threadIdx.x >> 7;
  for (int base = blockIdx.x * 2; base < N_NODES; base += gridDim.x * 2) {
    int n = base + sub;
    if (n < N_NODES) hs[sub][o] = emb[(long)node_ids[n] * HDIM + o];
    __syncthreads();
    if (n < N_NODES) {
      float acc = 0.f;
#pragma unroll
      for (int i = 0; i < HDIM; ++i) acc = fmaf(hs[sub][i], L[i * HDIM + o], acc);
      float v = acc + bias[o] + agg1[(long)n * HDIM + o];
      h1h[(long)n * HDIM + o] = f2h(fmaxf(v, 0.f));
    }
    __syncthreads();
  }
}

__global__ __launch_bounds__(256) void node_layer2a(
    const ushort_t* __restrict__ h1h, const float* __restrict__ loop2,
    const float* __restrict__ agg2, const float* __restrict__ bias2,
    float* __restrict__ outm) {
  __shared__ float L[HDIM * HDIM];
  __shared__ float hs[2][HDIM];
  for (int idx = threadIdx.x; idx < HDIM * HDIM; idx += 256) {
    int i = idx >> 7, oo = idx & 127;
    L[idx] = loop2[i * 256 + oo];
  }
  __syncthreads();
  int o = threadIdx.x & 127;
  int sub = threadIdx.x >> 7;
  for (int base = blockIdx.x * 2; base < N_NODES; base += gridDim.x * 2) {
    int n = base + sub;
    if (n < N_NODES) hs[sub][o] = h2f(h1h[(long)n * HDIM + o]);
    __syncthreads();
    if (n < N_NODES) {
      float acc = 0.f;
#pragma unroll
      for (int i = 0; i < HDIM; ++i) acc = fmaf(hs[sub][i], L[i * HDIM + o], acc);
      outm[(long)n * HDIM + o] = acc + bias2[o] + agg2[(long)n * 256 + o];
    }
    __syncthreads();
  }
}

__global__ __launch_bounds__(256) void node_layer2b(
    const ushort_t* __restrict__ h1h, const float* __restrict__ loop2,
    const float* __restrict__ agg2, const float* __restrict__ bias2,
    const float* __restrict__ eps, float* __restrict__ out) {
  __shared__ float L[HDIM * HDIM];
  __shared__ float hs[2][HDIM];
  for (int idx = threadIdx.x; idx < HDIM * HDIM; idx += 256) {
    int i = idx >> 7, oo = idx & 127;
    L[idx] = loop2[i * 256 + 128 + oo];
  }
  __syncthreads();
  int o = threadIdx.x & 127;
  int sub = threadIdx.x >> 7;
  for (int base = blockIdx.x * 2; base < N_NODES; base += gridDim.x * 2) {
    int n = base + sub;
    if (n < N_NODES) hs[sub][o] = h2f(h1h[(long)n * HDIM + o]);
    __syncthreads();
    if (n < N_NODES) {
      float acc = 0.f;
#pragma unroll
      for (int i = 0; i < HDIM; ++i) acc = fmaf(hs[sub][i], L[i * HDIM + o], acc);
      float hv = acc + bias2[128 + o] + agg2[(long)n * 256 + 128 + o];
      float sp = fmaxf(hv, 0.f) + log1pf(expf(-fabsf(hv)));
      float var = sp + 1e-8f;
      long off = (long)n * HDIM + o;
      out[off] = out[off] + sqrtf(var) * eps[off];
    }
    __syncthreads();
  }
}

extern "C" void kernel_launch(void* const* d_in, const int* in_sizes, int n_in,
                              void* d_out, int out_size, void* d_ws, size_t ws_size,
                              hipStream_t stream) {
  const int* node_ids = (const int*)d_in[0];
  const int* src      = (const int*)d_in[1];
  const int* dst      = (const int*)d_in[2];
  const int* etype    = (const int*)d_in[3];
  const float* norm   = (const float*)d_in[4];
  const float* emb    = (const float*)d_in[5];
  const float* W1     = (const float*)d_in[6];
  const float* loop1  = (const float*)d_in[7];
  const float* b1     = (const float*)d_in[8];
  const float* W2     = (const float*)d_in[9];
  const float* loop2  = (const float*)d_in[10];
  const float* b2     = (const float*)d_in[11];
  const float* eps    = (const float*)d_in[12];
  float* out = (float*)d_out;

  char* ws = (char*)d_ws;
  size_t off = 0;
  int* deg       = (int*)(ws + off); off += (size_t)N_NODES * 4;
  int* offsets   = (int*)(ws + off); off += (size_t)(N_NODES + 1) * 4;
  int* cursor    = (int*)(ws + off); off += (size_t)N_NODES * 4;
  int* ranges    = (int*)(ws + off); off += (size_t)(NW_AGG + 1) * 4;
  int4* rec      = (int4*)(ws + off); off += (size_t)N_EDGES * 16;
  float* agg2    = (float*)(ws + off); off += (size_t)N_NODES * 256 * 4;
  ushort_t* h0h  = (ushort_t*)(ws + off); off += (size_t)N_NODES * HDIM * 2;
  ushort_t* h1h  = (ushort_t*)(ws + off); off += (size_t)N_NODES * HDIM * 2;
  ushort_t* Wh1  = (ushort_t*)(ws + off); off += (size_t)NREL * NBLK * 64 * 2;
  ushort_t* Wh2  = (ushort_t*)(ws + off); off += (size_t)NREL * NBLK * 128 * 2;
  float* agg1 = out;  // agg1 lives in d_out (dead before node_layer2a writes)

  // ---- CSR build + f16 conversions ----
  hipMemsetAsync(deg, 0, (size_t)N_NODES * 4, stream);
  hipMemsetAsync(cursor, 0, (size_t)N_NODES * 4, stream);
  hist_deg<<<(N_EDGES + 255) / 256, 256, 0, stream>>>(dst, deg);
  conv_w1<<<(NREL * NBLK * 64 + 255) / 256, 256, 0, stream>>>(W1, Wh1);
  conv_w2<<<(NREL * NBLK * 128 + 255) / 256, 256, 0, stream>>>(W2, Wh2);
  scan_offsets<<<1, 1024, 0, stream>>>(deg, offsets);
  calc_ranges<<<(NW_AGG + 256) / 256, 256, 0, stream>>>(offsets, ranges);
  scatter_rec<<<(N_EDGES + 255) / 256, 256, 0, stream>>>(src, dst, etype, norm,
                                                         offsets, cursor, rec);
  conv_h0<<<(N_NODES * HDIM + 255) / 256, 256, 0, stream>>>(node_ids, emb, h0h);

  // ---- layer 1 ----
  agg_layer1<<<NW_AGG / 4, 256, 0, stream>>>(rec, offsets, ranges, h0h, Wh1, agg1);
  node_layer1<<<512, 256, 0, stream>>>(node_ids, emb, loop1, agg1, b1, h1h);

  // ---- layer 2 ----
  agg_layer2<<<NW_AGG / 4, 256, 0, stream>>>(rec, offsets, ranges, h1h, Wh2, agg2);
  node_layer2a<<<512, 256, 0, stream>>>(h1h, loop2, agg2, b2, out);
  node_layer2b<<<512, 256, 0, stream>>>(h1h, loop2, agg2, b2, eps, out);
}

// Round 9
// 1482.041 us; speedup vs baseline: 1.2338x; 1.2338x over previous
//
#include <hip/hip_runtime.h>
#include <math.h>

#define N_NODES 100000
#define N_EDGES 1600000
#define HDIM 128
#define NBLK 16
#define NREL 200
#define NW_AGG 8192  // balanced waves

typedef unsigned short ushort_t;
typedef unsigned int uint_t;
typedef _Float16 h2 __attribute__((ext_vector_type(2)));

__device__ __forceinline__ ushort_t f2h(float f) {
  _Float16 h = (_Float16)f;
  return __builtin_bit_cast(unsigned short, h);
}
__device__ __forceinline__ float h2f(ushort_t b) {
  return (float)__builtin_bit_cast(_Float16, b);
}

// acc += a.lo*b.lo + a.hi*b.hi  (packed f16 pairs, f32 accumulate)
#if defined(__has_builtin) && __has_builtin(__builtin_amdgcn_fdot2)
#define FDOT2(accv, au, bu)                                                    \
  accv = __builtin_amdgcn_fdot2(__builtin_bit_cast(h2, au),                    \
                                __builtin_bit_cast(h2, bu), accv, false);
#else
#define FDOT2(accv, au, bu)                                                    \
  {                                                                            \
    h2 av_ = __builtin_bit_cast(h2, au);                                       \
    h2 bv_ = __builtin_bit_cast(h2, bu);                                       \
    accv = fmaf((float)av_[0], (float)bv_[0], accv);                           \
    accv = fmaf((float)av_[1], (float)bv_[1], accv);                           \
  }
#endif

// ================= CSR build (dst -> packed edge records) =================
__global__ __launch_bounds__(256) void hist_deg(const int* __restrict__ dst,
                                                int* __restrict__ deg) {
  int e = blockIdx.x * 256 + threadIdx.x;
  if (e < N_EDGES) atomicAdd(&deg[dst[e]], 1);
}

// exclusive scan; also writes offsets[N_NODES] = E
__global__ __launch_bounds__(1024) void scan_offsets(const int* __restrict__ deg,
                                                     int* __restrict__ offsets) {
  __shared__ int wsum[16];
  __shared__ int carry_s;
  int tid = threadIdx.x, lane = tid & 63, wid = tid >> 6;
  if (tid == 0) carry_s = 0;
  __syncthreads();
  for (int base = 0; base < N_NODES; base += 1024) {
    int i = base + tid;
    int v = (i < N_NODES) ? deg[i] : 0;
    int x = v;
#pragma unroll
    for (int s = 1; s < 64; s <<= 1) {
      int t = __shfl_up(x, s);
      if (lane >= s) x += t;
    }
    if (lane == 63) wsum[wid] = x;
    __syncthreads();
    if (wid == 0) {
      int y = (lane < 16) ? wsum[lane] : 0;
#pragma unroll
      for (int s = 1; s < 16; s <<= 1) {
        int t = __shfl_up(y, s);
        if (lane >= s) y += t;
      }
      if (lane < 16) wsum[lane] = y;
    }
    __syncthreads();
    int carry = carry_s;
    int wbase = (wid > 0) ? wsum[wid - 1] : 0;
    if (i < N_NODES) offsets[i] = carry + wbase + (x - v);
    __syncthreads();
    if (tid == 0) carry_s = carry + wsum[15];
    __syncthreads();
  }
  if (tid == 0) offsets[N_NODES] = carry_s;  // == N_EDGES
}

__global__ __launch_bounds__(256) void scatter_rec(
    const int* __restrict__ src, const int* __restrict__ dst,
    const int* __restrict__ etype, const float* __restrict__ norm,
    const int* __restrict__ offsets, int* __restrict__ cursor,
    int4* __restrict__ rec) {
  int e = blockIdx.x * 256 + threadIdx.x;
  if (e >= N_EDGES) return;
  int d = dst[e];
  int pos = offsets[d] + atomicAdd(&cursor[d], 1);
  rec[pos] = make_int4(src[e], etype[e], __float_as_int(norm[e]), 0);
}

// wave w owns nodes [ranges[w], ranges[w+1])
__global__ __launch_bounds__(256) void calc_ranges(const int* __restrict__ offsets,
                                                   int* __restrict__ ranges) {
  int w = blockIdx.x * 256 + threadIdx.x;
  if (w > NW_AGG) return;
  if (w == NW_AGG) {
    ranges[w] = N_NODES;
    return;
  }
  long t = ((long)w * N_EDGES + NW_AGG - 1) / NW_AGG;  // ceil(w*E/NW)
  int lo = 0, hi = N_NODES;
  while (lo < hi) {
    int mid = (lo + hi) >> 1;
    if ((long)offsets[mid] >= t) hi = mid;
    else lo = mid + 1;
  }
  ranges[w] = lo;
}

// f16 copy of gathered embeddings
__global__ __launch_bounds__(256) void conv_h0(const int* __restrict__ node_ids,
                                               const float* __restrict__ emb,
                                               ushort_t* __restrict__ h0h) {
  long gid = (long)blockIdx.x * 256 + threadIdx.x;
  if (gid >= (long)N_NODES * HDIM) return;
  int n = (int)(gid >> 7);
  int o = (int)(gid & 127);
  h0h[gid] = f2h(emb[(long)node_ids[n] * HDIM + o]);
}

// W1 (R,NB,8,8) fp32 -> Wh1 [rb][g(4)][c(2)][ip(4)][hi(2)] f16 (i = ip*2+hi, o = g*2+c)
__global__ __launch_bounds__(256) void conv_w1(const float* __restrict__ W,
                                               ushort_t* __restrict__ Wh) {
  int idx = blockIdx.x * 256 + threadIdx.x;
  if (idx >= NREL * NBLK * 64) return;
  int rb = idx >> 6, i = (idx >> 3) & 7, o = idx & 7;
  int g = o >> 1, c = o & 1, ip = i >> 1, hi = i & 1;
  Wh[(((rb * 4 + g) * 2 + c) * 4 + ip) * 2 + hi] = f2h(W[idx]);
}

// W2 (R,NB,8,16) fp32 -> Wh2 [rb][g(4)][c(4)][ip(4)][hi(2)] f16 (i = ip*2+hi, o = g*4+c)
__global__ __launch_bounds__(256) void conv_w2(const float* __restrict__ W,
                                               ushort_t* __restrict__ Wh) {
  int idx = blockIdx.x * 256 + threadIdx.x;
  if (idx >= NREL * NBLK * 128) return;
  int rb = idx >> 7, i = (idx >> 4) & 7, o = idx & 15;
  int g = o >> 2, c = o & 3, ip = i >> 1, hi = i & 1;
  Wh[(((rb * 4 + g) * 4 + c) * 4 + ip) * 2 + hi] = f2h(W[idx]);
}

// ================= Layer-1 aggregation: balanced waves =================
// lane l: block b = l>>2, col-group g = l&3 (cols g*2, g*2+1)
__global__ __launch_bounds__(256, 4) void agg_layer1(
    const int4* __restrict__ rec, const int* __restrict__ offsets,
    const int* __restrict__ ranges, const ushort_t* __restrict__ h0h,
    const ushort_t* __restrict__ Wh, float* __restrict__ agg) {
  int w = blockIdx.x * 4 + (threadIdx.x >> 6);
  int l = threadIdx.x & 63;
  int b = l >> 2, g = l & 3;
  int lo = ranges[w], hi = ranges[w + 1];
  if (lo >= hi) return;
  int estart = offsets[lo];
  int ecnt = offsets[hi] - estart;
  int cur = lo;
  int next_b = offsets[lo + 1];
  float acc0 = 0.f, acc1 = 0.f;

#define FLUSH1                                                                 \
  {                                                                            \
    float2 res = {acc0, acc1};                                                 \
    *(float2*)(agg + (long)cur * HDIM + l * 2) = res;                          \
    acc0 = acc1 = 0.f;                                                         \
    ++cur;                                                                     \
    next_b = offsets[cur + 1];                                                 \
  }
#define BCHK1(kk)                                                              \
  {                                                                            \
    int eid = estart + c0 + kk;                                                \
    while (eid == next_b) FLUSH1                                               \
  }
#define LOAD1(U, W0, W1, kk)                                                   \
  {                                                                            \
    int ss = __shfl(r.x, kk), tt = __shfl(r.y, kk);                            \
    U = *(const uint4*)(h0h + ((long)ss << 7) + (b << 3));                     \
    const uint4* Wp =                                                          \
        (const uint4*)(Wh + (((size_t)((tt << 4) + b) << 2) + g) * 16);        \
    W0 = Wp[0];                                                                \
    W1 = Wp[1];                                                                \
  }
#define COMP1(U, W0, W1, kk)                                                   \
  {                                                                            \
    float nn = __uint_as_float((uint_t)__shfl(r.z, kk));                       \
    float p0 = 0.f, p1 = 0.f;                                                  \
    FDOT2(p0, U.x, W0.x) FDOT2(p0, U.y, W0.y)                                  \
    FDOT2(p0, U.z, W0.z) FDOT2(p0, U.w, W0.w)                                  \
    FDOT2(p1, U.x, W1.x) FDOT2(p1, U.y, W1.y)                                  \
    FDOT2(p1, U.z, W1.z) FDOT2(p1, U.w, W1.w)                                  \
    acc0 = fmaf(p0, nn, acc0);                                                 \
    acc1 = fmaf(p1, nn, acc1);                                                 \
  }

  for (int c0 = 0; c0 < ecnt; c0 += 64) {
    int m = min(64, ecnt - c0);
    int4 r = make_int4(0, 0, 0, 0);
    if (l < m) r = rec[estart + c0 + l];
    uint4 uA, wA0, wA1, uB, wB0, wB1;
    LOAD1(uA, wA0, wA1, 0)
    int k = 0;
    while (true) {
      BCHK1(k)
      if (k + 1 < m) LOAD1(uB, wB0, wB1, k + 1)
      COMP1(uA, wA0, wA1, k)
      if (++k >= m) break;
      BCHK1(k)
      if (k + 1 < m) LOAD1(uA, wA0, wA1, k + 1)
      COMP1(uB, wB0, wB1, k)
      if (++k >= m) break;
    }
  }
  // final flush: last node + trailing deg-0 nodes
  while (cur < hi) {
    float2 res = {acc0, acc1};
    *(float2*)(agg + (long)cur * HDIM + l * 2) = res;
    acc0 = acc1 = 0.f;
    ++cur;
  }
#undef FLUSH1
#undef BCHK1
#undef LOAD1
#undef COMP1
}

// ================= Layer-2 aggregation: balanced waves =================
// lane l: block b = l>>2, col-group g = l&3 (cols g*4..g*4+3)
__global__ __launch_bounds__(256, 4) void agg_layer2(
    const int4* __restrict__ rec, const int* __restrict__ offsets,
    const int* __restrict__ ranges, const ushort_t* __restrict__ h1h,
    const ushort_t* __restrict__ Wh, float* __restrict__ agg) {
  int w = blockIdx.x * 4 + (threadIdx.x >> 6);
  int l = threadIdx.x & 63;
  int b = l >> 2, g = l & 3;
  int lo = ranges[w], hi = ranges[w + 1];
  if (lo >= hi) return;
  int estart = offsets[lo];
  int ecnt = offsets[hi] - estart;
  int cur = lo;
  int next_b = offsets[lo + 1];
  float ax = 0.f, ay = 0.f, az = 0.f, aw = 0.f;

#define FLUSH2                                                                 \
  {                                                                            \
    float4 res = {ax, ay, az, aw};                                             \
    *(float4*)(agg + (long)cur * 256 + l * 4) = res;                           \
    ax = ay = az = aw = 0.f;                                                   \
    ++cur;                                                                     \
    next_b = offsets[cur + 1];                                                 \
  }
#define BCHK2(kk)                                                              \
  {                                                                            \
    int eid = estart + c0 + kk;                                                \
    while (eid == next_b) FLUSH2                                               \
  }
#define LOAD2(U, Q0, Q1, Q2, Q3, kk)                                           \
  {                                                                            \
    int ss = __shfl(r.x, kk), tt = __shfl(r.y, kk);                            \
    U = *(const uint4*)(h1h + ((long)ss << 7) + (b << 3));                     \
    const uint4* Wp =                                                          \
        (const uint4*)(Wh + (((size_t)((tt << 4) + b) << 2) + g) * 32);        \
    Q0 = Wp[0];                                                                \
    Q1 = Wp[1];                                                                \
    Q2 = Wp[2];                                                                \
    Q3 = Wp[3];                                                                \
  }
#define COMP2(U, Q0, Q1, Q2, Q3, kk)                                           \
  {                                                                            \
    float nn = __uint_as_float((uint_t)__shfl(r.z, kk));                       \
    float px = 0.f, py = 0.f, pz = 0.f, pw = 0.f;                              \
    FDOT2(px, U.x, Q0.x) FDOT2(px, U.y, Q0.y)                                  \
    FDOT2(px, U.z, Q0.z) FDOT2(px, U.w, Q0.w)                                  \
    FDOT2(py, U.x, Q1.x) FDOT2(py, U.y, Q1.y)                                  \
    FDOT2(py, U.z, Q1.z) FDOT2(py, U.w, Q1.w)                                  \
    FDOT2(pz, U.x, Q2.x) FDOT2(pz, U.y, Q2.y)                                  \
    FDOT2(pz, U.z, Q2.z) FDOT2(pz, U.w, Q2.w)                                  \
    FDOT2(pw, U.x, Q3.x) FDOT2(pw, U.y, Q3.y)                                  \
    FDOT2(pw, U.z, Q3.z) FDOT2(pw, U.w, Q3.w)                                  \
    ax = fmaf(px, nn, ax);                                                     \
    ay = fmaf(py, nn, ay);                                                     \
    az = fmaf(pz, nn, az);                                                     \
    aw = fmaf(pw, nn, aw);                                                     \
  }

  for (int c0 = 0; c0 < ecnt; c0 += 64) {
    int m = min(64, ecnt - c0);
    int4 r = make_int4(0, 0, 0, 0);
    if (l < m) r = rec[estart + c0 + l];
    uint4 uA, qA0, qA1, qA2, qA3, uB, qB0, qB1, qB2, qB3;
    LOAD2(uA, qA0, qA1, qA2, qA3, 0)
    int k = 0;
    while (true) {
      BCHK2(k)
      if (k + 1 < m) LOAD2(uB, qB0, qB1, qB2, qB3, k + 1)
      COMP2(uA, qA0, qA1, qA2, qA3, k)
      if (++k >= m) break;
      BCHK2(k)
      if (k + 1 < m) LOAD2(uA, qA0, qA1, qA2, qA3, k + 1)
      COMP2(uB, qB0, qB1, qB2, qB3, k)
      if (++k >= m) break;
    }
  }
  while (cur < hi) {
    float4 res = {ax, ay, az, aw};
    *(float4*)(agg + (long)cur * 256 + l * 4) = res;
    ax = ay = az = aw = 0.f;
    ++cur;
  }
#undef FLUSH2
#undef BCHK2
#undef LOAD2
#undef COMP2
}

// ================= Node kernels (dense self-loop + epilogue) =================
__global__ __launch_bounds__(256) void node_layer1(
    const int* __restrict__ node_ids, const float* __restrict__ emb,
    const float* __restrict__ loop1, const float* __restrict__ agg1,
    const float* __restrict__ bias, ushort_t* __restrict__ h1h) {
  __shared__ float L[HDIM * HDIM];
  __shared__ float hs[2][HDIM];
  for (int idx = threadIdx.x; idx < HDIM * HDIM; idx += 256) L[idx] = loop1[idx];
  __syncthreads();
  int o = threadIdx.x & 127;
  int sub = threadIdx.x >> 7;
  for (int base = blockIdx.x * 2; base < N_NODES; base += gridDim.x * 2) {
    int n = base + sub;
    if (n < N_NODES) hs[sub][o] = emb[(long)node_ids[n] * HDIM + o];
    __syncthreads();
    if (n < N_NODES) {
      float acc = 0.f;
#pragma unroll
      for (int i = 0; i < HDIM; ++i) acc = fmaf(hs[sub][i], L[i * HDIM + o], acc);
      float v = acc + bias[o] + agg1[(long)n * HDIM + o];
      h1h[(long)n * HDIM + o] = f2h(fmaxf(v, 0.f));
    }
    __syncthreads();
  }
}

__global__ __launch_bounds__(256) void node_layer2a(
    const ushort_t* __restrict__ h1h, const float* __restrict__ loop2,
    const float* __restrict__ agg2, const float* __restrict__ bias2,
    float* __restrict__ outm) {
  __shared__ float L[HDIM * HDIM];
  __shared__ float hs[2][HDIM];
  for (int idx = threadIdx.x; idx < HDIM * HDIM; idx += 256) {
    int i = idx >> 7, oo = idx & 127;
    L[idx] = loop2[i * 256 + oo];
  }
  __syncthreads();
  int o = threadIdx.x & 127;
  int sub = threadIdx.x >> 7;
  for (int base = blockIdx.x * 2; base < N_NODES; base += gridDim.x * 2) {
    int n = base + sub;
    if (n < N_NODES) hs[sub][o] = h2f(h1h[(long)n * HDIM + o]);
    __syncthreads();
    if (n < N_NODES) {
      float acc = 0.f;
#pragma unroll
      for (int i = 0; i < HDIM; ++i) acc = fmaf(hs[sub][i], L[i * HDIM + o], acc);
      outm[(long)n * HDIM + o] = acc + bias2[o] + agg2[(long)n * 256 + o];
    }
    __syncthreads();
  }
}

__global__ __launch_bounds__(256) void node_layer2b(
    const ushort_t* __restrict__ h1h, const float* __restrict__ loop2,
    const float* __restrict__ agg2, const float* __restrict__ bias2,
    const float* __restrict__ eps, float* __restrict__ out) {
  __shared__ float L[HDIM * HDIM];
  __shared__ float hs[2][HDIM];
  for (int idx = threadIdx.x; idx < HDIM * HDIM; idx += 256) {
    int i = idx >> 7, oo = idx & 127;
    L[idx] = loop2[i * 256 + 128 + oo];
  }
  __syncthreads();
  int o = threadIdx.x & 127;
  int sub = threadIdx.x >> 7;
  for (int base = blockIdx.x * 2; base < N_NODES; base += gridDim.x * 2) {
    int n = base + sub;
    if (n < N_NODES) hs[sub][o] = h2f(h1h[(long)n * HDIM + o]);
    __syncthreads();
    if (n < N_NODES) {
      float acc = 0.f;
#pragma unroll
      for (int i = 0; i < HDIM; ++i) acc = fmaf(hs[sub][i], L[i * HDIM + o], acc);
      float hv = acc + bias2[128 + o] + agg2[(long)n * 256 + 128 + o];
      float sp = fmaxf(hv, 0.f) + log1pf(expf(-fabsf(hv)));
      float var = sp + 1e-8f;
      long off = (long)n * HDIM + o;
      out[off] = out[off] + sqrtf(var) * eps[off];
    }
    __syncthreads();
  }
}

extern "C" void kernel_launch(void* const* d_in, const int* in_sizes, int n_in,
                              void* d_out, int out_size, void* d_ws, size_t ws_size,
                              hipStream_t stream) {
  const int* node_ids = (const int*)d_in[0];
  const int* src      = (const int*)d_in[1];
  const int* dst      = (const int*)d_in[2];
  const int* etype    = (const int*)d_in[3];
  const float* norm   = (const float*)d_in[4];
  const float* emb    = (const float*)d_in[5];
  const float* W1     = (const float*)d_in[6];
  const float* loop1  = (const float*)d_in[7];
  const float* b1     = (const float*)d_in[8];
  const float* W2     = (const float*)d_in[9];
  const float* loop2  = (const float*)d_in[10];
  const float* b2     = (const float*)d_in[11];
  const float* eps    = (const float*)d_in[12];
  float* out = (float*)d_out;

  char* ws = (char*)d_ws;
  size_t off = 0;
  int* deg       = (int*)(ws + off); off += (size_t)N_NODES * 4;
  int* offsets   = (int*)(ws + off); off += (size_t)(N_NODES + 1) * 4;
  int* cursor    = (int*)(ws + off); off += (size_t)N_NODES * 4;
  int* ranges    = (int*)(ws + off); off += (size_t)(NW_AGG + 1) * 4;
  int4* rec      = (int4*)(ws + off); off += (size_t)N_EDGES * 16;
  float* agg2    = (float*)(ws + off); off += (size_t)N_NODES * 256 * 4;
  ushort_t* h0h  = (ushort_t*)(ws + off); off += (size_t)N_NODES * HDIM * 2;
  ushort_t* h1h  = (ushort_t*)(ws + off); off += (size_t)N_NODES * HDIM * 2;
  ushort_t* Wh1  = (ushort_t*)(ws + off); off += (size_t)NREL * NBLK * 64 * 2;
  ushort_t* Wh2  = (ushort_t*)(ws + off); off += (size_t)NREL * NBLK * 128 * 2;
  float* agg1 = out;  // agg1 lives in d_out (dead before node_layer2a writes)

  // ---- CSR build + f16 conversions ----
  hipMemsetAsync(deg, 0, (size_t)N_NODES * 4, stream);
  hipMemsetAsync(cursor, 0, (size_t)N_NODES * 4, stream);
  hist_deg<<<(N_EDGES + 255) / 256, 256, 0, stream>>>(dst, deg);
  conv_w1<<<(NREL * NBLK * 64 + 255) / 256, 256, 0, stream>>>(W1, Wh1);
  conv_w2<<<(NREL * NBLK * 128 + 255) / 256, 256, 0, stream>>>(W2, Wh2);
  scan_offsets<<<1, 1024, 0, stream>>>(deg, offsets);
  calc_ranges<<<(NW_AGG + 256) / 256, 256, 0, stream>>>(offsets, ranges);
  scatter_rec<<<(N_EDGES + 255) / 256, 256, 0, stream>>>(src, dst, etype, norm,
                                                         offsets, cursor, rec);
  conv_h0<<<(N_NODES * HDIM + 255) / 256, 256, 0, stream>>>(node_ids, emb, h0h);

  // ---- layer 1 ----
  agg_layer1<<<NW_AGG / 4, 256, 0, stream>>>(rec, offsets, ranges, h0h, Wh1, agg1);
  node_layer1<<<512, 256, 0, stream>>>(node_ids, emb, loop1, agg1, b1, h1h);

  // ---- layer 2 ----
  agg_layer2<<<NW_AGG / 4, 256, 0, stream>>>(rec, offsets, ranges, h1h, Wh2, agg2);
  node_layer2a<<<512, 256, 0, stream>>>(h1h, loop2, agg2, b2, out);
  node_layer2b<<<512, 256, 0, stream>>>(h1h, loop2, agg2, b2, eps, out);
}